// Round 5
// baseline (1600.089 us; speedup 1.0000x reference)
//
#include <hip/hip_runtime.h>
#include <hip/hip_bf16.h>

#define B_ 8
#define C_ 512
#define N_ 16384
#define R_ 64
#define EPS 1e-6f

typedef float  f32x4  __attribute__((ext_vector_type(4)));
typedef short  bf16x4 __attribute__((ext_vector_type(4)));
typedef short  bf16x8 __attribute__((ext_vector_type(8)));

#define DI __device__ __forceinline__

DI short f2bf(float f) {
    union { float f; unsigned u; } a; a.f = f;
    unsigned r = a.u + 0x7fffu + ((a.u >> 16) & 1u);
    return (short)(r >> 16);
}
DI float bf2f(short s) {
    union { unsigned u; float f; } a;
    a.u = ((unsigned)(unsigned short)s) << 16;
    return a.f;
}
DI unsigned pk2(float lo, float hi) {
    union { __hip_bfloat162 h; unsigned u; } c;
    c.h = __float22bfloat162_rn(make_float2(lo, hi));
    return c.u;
}

union BV { bf16x8 v; bf16x4 h[2]; };
DI bf16x8 ldfrag(const short* p) {
    BV u;
    u.h[0] = *(const bf16x4*)p;
    u.h[1] = *(const bf16x4*)(p + 4);
    return u.v;
}
DI f32x4 mfma16(bf16x8 a, bf16x8 b, f32x4 c) {
    return __builtin_amdgcn_mfma_f32_16x16x32_bf16(a, b, c, 0, 0, 0);
}

// ---------------------------------------------------------------------------
// prep: bases [512][64] f32 -> basesT [8][64][512] f32 + bf16; w_in -> bf16
// ---------------------------------------------------------------------------
__global__ __launch_bounds__(256)
void k_prep(const float* __restrict__ bases, float* __restrict__ basesT,
            short* __restrict__ basesTb, const float* __restrict__ w_in,
            short* __restrict__ wbf) {
    int idx = blockIdx.x * 256 + threadIdx.x;        // 262144
    const int d = idx & 511;
    const int r = (idx >> 9) & 63;
    const float v = bases[d * 64 + r];
    basesT[idx]  = v;
    basesTb[idx] = f2bf(v);
    wbf[idx] = f2bf(w_in[idx]);
}

// ---------------------------------------------------------------------------
// conv1: Ht[n][c] = relu(Win @ X + b_in)^T   (X [C][N] f32 -> Ht [N][C] bf16)
// tile 128(m=c) x 128(n), BK=32, 256 thr (2x2 waves of 64x64)
// ---------------------------------------------------------------------------
__global__ __launch_bounds__(256)
void k_conv1(const short* __restrict__ Wbf, const float* __restrict__ bias,
             const float* __restrict__ X, short* __restrict__ Ht) {
    const int nb = blockIdx.x * 128, mb = blockIdx.y * 128, bb = blockIdx.z;
    const float* Xb = X + (size_t)bb * C_ * N_;
    short* HtB = Ht + (size_t)bb * N_ * C_;
    __shared__ short As[128 * 36];
    __shared__ short Bs[128 * 36];
    const int t = threadIdx.x;
    const int lane = t & 63, wave = t >> 6;
    const int wm = wave >> 1, wn = wave & 1;
    const int fr = lane & 15, fg = lane >> 4;
    f32x4 zero4 = {0.f, 0.f, 0.f, 0.f};
    f32x4 acc[4][4];
    for (int i = 0; i < 4; i++) for (int j = 0; j < 4; j++) acc[i][j] = zero4;

    const int an_row = t >> 2, an_kc = (t & 3) * 8;          // A copy
    const int bkp = t >> 4;                                  // B k-pair

    for (int kb = 0; kb < C_; kb += 32) {
        {   // stage A: copy Wbf rows (k-contig)
#pragma unroll
            for (int i = 0; i < 2; i++) {
                const int row = an_row + 64 * i;
                const short* src = Wbf + (size_t)(mb + row) * C_ + kb + an_kc;
                short* dst = &As[row * 36 + an_kc];
                *(bf16x4*)dst = *(const bf16x4*)src;
                *(bf16x4*)(dst + 4) = *(const bf16x4*)(src + 4);
            }
        }
        {   // stage B transposed: X[k][n] -> Bs[n*36+k]; float4 loads + pk2
#pragma unroll
            for (int i = 0; i < 2; i++) {
                const int n0 = 4 * ((t & 15) + 16 * i);
                const float* r0 = Xb + (size_t)(kb + 2 * bkp) * N_ + nb + n0;
                float4 va = *(const float4*)r0;
                float4 vb = *(const float4*)(r0 + N_);
                const float* pa = (const float*)&va;
                const float* pb = (const float*)&vb;
#pragma unroll
                for (int j = 0; j < 4; j++)
                    *(unsigned*)&Bs[(n0 + j) * 36 + 2 * bkp] = pk2(pa[j], pb[j]);
            }
        }
        __syncthreads();
        bf16x8 af[4], bv[4];
#pragma unroll
        for (int mi = 0; mi < 4; mi++) af[mi] = ldfrag(&As[(wm * 64 + mi * 16 + fr) * 36 + fg * 8]);
#pragma unroll
        for (int ni = 0; ni < 4; ni++) bv[ni] = ldfrag(&Bs[(wn * 64 + ni * 16 + fr) * 36 + fg * 8]);
#pragma unroll
        for (int mi = 0; mi < 4; mi++)
#pragma unroll
            for (int ni = 0; ni < 4; ni++)
                acc[mi][ni] = mfma16(af[mi], bv[ni], acc[mi][ni]);
        __syncthreads();
    }
    // epilogue: packed b64 stores to Ht[n][c]
#pragma unroll
    for (int mi = 0; mi < 4; mi++) {
        const int c0 = mb + wm * 64 + mi * 16 + fg * 4;
        const float4 b4 = *(const float4*)&bias[c0];
        const float* bp = (const float*)&b4;
#pragma unroll
        for (int ni = 0; ni < 4; ni++) {
            const int n = nb + wn * 64 + ni * 16 + fr;
            bf16x4 pk;
#pragma unroll
            for (int j = 0; j < 4; j++) {
                float v = acc[mi][ni][j] + bp[j];
                pk[j] = f2bf(v > 0.f ? v : 0.f);
            }
            *(bf16x4*)&HtB[(size_t)n * C_ + c0] = pk;
        }
    }
}

// ---------------------------------------------------------------------------
// k_coef: num[n][r] = Ht @ basesT^T (K=512); UPDATE: den[n][r] via btb (K=64),
// coef[r][n] *= num/(den+eps); else coef = softmax_r(num).
// acc layout D[row=n][col=r]: lane holds 4 consecutive n (j) at r=rt*16+fr.
// ---------------------------------------------------------------------------
template<int UPDATE>
__global__ __launch_bounds__(256)
void k_coef(const short* __restrict__ basesTb, const short* __restrict__ Ht,
            const short* __restrict__ btb, short* __restrict__ coef) {
    const int nb = blockIdx.x * 256, bb = blockIdx.y;
    const short* HtB = Ht + (size_t)bb * N_ * C_;
    const short* bT = basesTb + (size_t)bb * R_ * C_;
    short* coefB = coef + (size_t)bb * R_ * N_;
    __shared__ short As[64 * 36];
    __shared__ short Bs[256 * 44];
    __shared__ short Ds[64 * 68];
    const int t = threadIdx.x;
    const int lane = t & 63, wave = t >> 6;
    const int fr = lane & 15, fg = lane >> 4;
    f32x4 zero4 = {0.f, 0.f, 0.f, 0.f};
    f32x4 accN[4][4];   // [nt][rt]
    for (int i = 0; i < 4; i++) for (int j = 0; j < 4; j++) accN[i][j] = zero4;

    // phase 1: num = Ht-rows x bases-rows (contract d)
    for (int kb = 0; kb < C_; kb += 32) {
        {   // A: basesT bf16 copy (rows r, k-contig)
            const int row = t >> 2, kc = (t & 3) * 8;
            const short* src = bT + row * C_ + kb + kc;
            short* dst = &As[row * 36 + kc];
            *(bf16x4*)dst = *(const bf16x4*)src;
            *(bf16x4*)(dst + 4) = *(const bf16x4*)(src + 4);
        }
        {   // B: plain copy of Ht rows (c-contig) -> Bs[n*44 + k]
            const short* src = HtB + (size_t)(nb + t) * C_ + kb;
            short* dst = &Bs[t * 44];
#pragma unroll
            for (int s = 0; s < 4; s++) {
                BV u; u.v = *(const bf16x8*)(src + 8 * s);
                *(bf16x4*)(dst + 8 * s) = u.h[0];
                *(bf16x4*)(dst + 8 * s + 4) = u.h[1];
            }
        }
        __syncthreads();
        bf16x8 hf[4], bfr[4];
#pragma unroll
        for (int nt = 0; nt < 4; nt++) hf[nt] = ldfrag(&Bs[(wave * 64 + nt * 16 + fr) * 44 + fg * 8]);
#pragma unroll
        for (int rt = 0; rt < 4; rt++) bfr[rt] = ldfrag(&As[(rt * 16 + fr) * 36 + fg * 8]);
#pragma unroll
        for (int nt = 0; nt < 4; nt++)
#pragma unroll
            for (int rt = 0; rt < 4; rt++)
                accN[nt][rt] = mfma16(hf[nt], bfr[rt], accN[nt][rt]);
        __syncthreads();
    }

    if (UPDATE) {
        f32x4 accD[4][4];
        for (int i = 0; i < 4; i++) for (int j = 0; j < 4; j++) accD[i][j] = zero4;
        {   // stage btb [64][64] -> Ds (stride 68)
            const short* bt = btb + bb * R_ * R_;
#pragma unroll
            for (int i = 0; i < 2; i++) {
                const int row = t & 63, kc8 = ((t >> 6) + 4 * i) * 8;
                const short* src = bt + row * 64 + kc8;
                short* dst = &Ds[row * 68 + kc8];
                *(bf16x4*)dst = *(const bf16x4*)src;
                *(bf16x4*)(dst + 4) = *(const bf16x4*)(src + 4);
            }
        }
        // phase 2: den[n][r] = coefT-rows x btb-rows (contract s), two K=32 substeps
        for (int ks = 0; ks < 2; ks++) {
            const int sp = t >> 4;              // s-pair 0..15
            const int s0 = ks * 32 + 2 * sp;
#pragma unroll
            for (int p = 0; p < 8; p++) {
                const int n0 = 2 * ((t & 15) + 16 * p);
                const unsigned ra = *(const unsigned*)(coefB + (size_t)s0 * N_ + nb + n0);
                const unsigned rb = *(const unsigned*)(coefB + (size_t)(s0 + 1) * N_ + nb + n0);
                *(unsigned*)&Bs[n0 * 44 + 2 * sp] = (ra & 0xffffu) | (rb << 16);
                *(unsigned*)&Bs[(n0 + 1) * 44 + 2 * sp] = (ra >> 16) | (rb & 0xffff0000u);
            }
            __syncthreads();
            bf16x8 cf[4], df[4];
#pragma unroll
            for (int nt = 0; nt < 4; nt++) cf[nt] = ldfrag(&Bs[(wave * 64 + nt * 16 + fr) * 44 + fg * 8]);
#pragma unroll
            for (int rt = 0; rt < 4; rt++) df[rt] = ldfrag(&Ds[(rt * 16 + fr) * 68 + ks * 32 + fg * 8]);
#pragma unroll
            for (int nt = 0; nt < 4; nt++)
#pragma unroll
                for (int rt = 0; rt < 4; rt++)
                    accD[nt][rt] = mfma16(cf[nt], df[rt], accD[nt][rt]);
            __syncthreads();
        }
        // phase 3: multiplicative update, b64 packed RMW
#pragma unroll
        for (int nt = 0; nt < 4; nt++)
#pragma unroll
            for (int rt = 0; rt < 4; rt++) {
                const int r = rt * 16 + fr;
                const int n0 = nb + wave * 64 + nt * 16 + fg * 4;
                short* p = coefB + (size_t)r * N_ + n0;
                bf16x4 old = *(const bf16x4*)p;
                bf16x4 nw;
#pragma unroll
                for (int j = 0; j < 4; j++)
                    nw[j] = f2bf(bf2f(old[j]) * accN[nt][rt][j] / (accD[nt][rt][j] + EPS));
                *(bf16x4*)p = nw;
            }
    } else {
        // softmax over r (64) per column n; r lives across rt x fr-lanes
#pragma unroll
        for (int nt = 0; nt < 4; nt++) {
            float mx[4], sm[4];
#pragma unroll
            for (int j = 0; j < 4; j++) {
                float m = accN[nt][0][j];
#pragma unroll
                for (int rt = 1; rt < 4; rt++) m = fmaxf(m, accN[nt][rt][j]);
                m = fmaxf(m, __shfl_xor(m, 1, 64));
                m = fmaxf(m, __shfl_xor(m, 2, 64));
                m = fmaxf(m, __shfl_xor(m, 4, 64));
                m = fmaxf(m, __shfl_xor(m, 8, 64));
                mx[j] = m; sm[j] = 0.f;
            }
#pragma unroll
            for (int rt = 0; rt < 4; rt++)
#pragma unroll
                for (int j = 0; j < 4; j++) {
                    float e = __expf(accN[nt][rt][j] - mx[j]);
                    accN[nt][rt][j] = e;
                    sm[j] += e;
                }
#pragma unroll
            for (int j = 0; j < 4; j++) {
                float s = sm[j];
                s += __shfl_xor(s, 1, 64);
                s += __shfl_xor(s, 2, 64);
                s += __shfl_xor(s, 4, 64);
                s += __shfl_xor(s, 8, 64);
                sm[j] = 1.f / s;
            }
#pragma unroll
            for (int rt = 0; rt < 4; rt++) {
                const int r = rt * 16 + fr;
                const int n0 = nb + wave * 64 + nt * 16 + fg * 4;
                bf16x4 pk;
#pragma unroll
                for (int j = 0; j < 4; j++) pk[j] = f2bf(accN[nt][rt][j] * sm[j]);
                *(bf16x4*)&coefB[(size_t)r * N_ + n0] = pk;
            }
        }
    }
}

// ---------------------------------------------------------------------------
// k_tn: C[r][dd] = sum_k A[r,k]*B[dd,k]
// MODE 0: A=coef, B=[H(from Ht, transposed) ; coef] rows (576), split-K partials
// MODE 1: A=B=basesT -> btb bf16
// MODE 2: A=basesT, B=Wout(f32) -> Wfused bf16 stored [o][r]
// ---------------------------------------------------------------------------
template<int MODE>
__global__ __launch_bounds__(256)
void k_tn(const short* __restrict__ coef, const short* __restrict__ Ht,
          const short* __restrict__ basesTb, const float* __restrict__ Wout,
          float* __restrict__ parts, short* __restrict__ btb, short* __restrict__ wf) {
    const int ddt = blockIdx.x, ch = blockIdx.y, bb = blockIdx.z;
    const int kLen = (MODE == 0) ? 2048 : 512;
    const int k0g = ch * kLen;
    const short* Ap; int lda;
    if (MODE == 0) { Ap = coef + (size_t)bb * R_ * N_; lda = N_; }
    else           { Ap = basesTb + (size_t)bb * R_ * C_; lda = C_; }
    const short* HtB = Ht + (size_t)bb * N_ * C_;
    __shared__ short As[64 * 68];
    __shared__ short Bs[64 * 68];
    const int t = threadIdx.x;
    const int lane = t & 63, wave = t >> 6;
    const int fr = lane & 15, fg = lane >> 4;
    f32x4 zero4 = {0.f, 0.f, 0.f, 0.f};
    f32x4 acc[4];
    for (int i = 0; i < 4; i++) acc[i] = zero4;

    for (int kb = 0; kb < kLen; kb += 64) {
#pragma unroll
        for (int i = 0; i < 2; i++) {   // stage A
            const int kg = (t & 7) * 8, row = (t >> 3) + 32 * i;
            const short* src = Ap + (size_t)row * lda + k0g + kb + kg;
            short* dst = &As[row * 68 + kg];
            *(bf16x4*)dst = *(const bf16x4*)src;
            *(bf16x4*)(dst + 4) = *(const bf16x4*)(src + 4);
        }
        // stage B
        if (MODE == 0 && ddt < 8) {
            // transpose from Ht: B[dd][n] = Ht[n][dd]
            const int dd0 = 2 * (t & 31);
#pragma unroll
            for (int i = 0; i < 4; i++) {
                const int n0 = 2 * ((t >> 5) + 8 * i);
                const unsigned ra = *(const unsigned*)(HtB + (size_t)(k0g + kb + n0) * C_ + ddt * 64 + dd0);
                const unsigned rb = *(const unsigned*)(HtB + (size_t)(k0g + kb + n0 + 1) * C_ + ddt * 64 + dd0);
                *(unsigned*)&Bs[dd0 * 68 + n0] = (ra & 0xffffu) | (rb << 16);
                *(unsigned*)&Bs[(dd0 + 1) * 68 + n0] = (ra >> 16) | (rb & 0xffff0000u);
            }
        } else {
#pragma unroll
            for (int i = 0; i < 2; i++) {
                const int kg = (t & 7) * 8, row = (t >> 3) + 32 * i;
                const int dd = ddt * 64 + row;
                short* dst = &Bs[row * 68 + kg];
                if (MODE == 2) {
                    const float* src = Wout + (size_t)dd * C_ + kb + kg;
                    float4 v0 = *(const float4*)src;
                    float4 v1 = *(const float4*)(src + 4);
                    *(unsigned*)dst = pk2(v0.x, v0.y);
                    *(unsigned*)(dst + 2) = pk2(v0.z, v0.w);
                    *(unsigned*)(dst + 4) = pk2(v1.x, v1.y);
                    *(unsigned*)(dst + 6) = pk2(v1.z, v1.w);
                } else {
                    const short* src;
                    if (MODE == 0)   // ddt==8: coef rows (ctc part)
                        src = coef + (size_t)bb * R_ * N_ + (size_t)(ddt * 64 + row - C_) * N_ + k0g + kb + kg;
                    else
                        src = basesTb + (size_t)bb * R_ * C_ + (size_t)dd * C_ + kb + kg;
                    *(bf16x4*)dst = *(const bf16x4*)src;
                    *(bf16x4*)(dst + 4) = *(const bf16x4*)(src + 4);
                }
            }
        }
        __syncthreads();
#pragma unroll
        for (int kk = 0; kk < 2; kk++) {
            bf16x8 a = ldfrag(&As[(wave * 16 + fr) * 68 + kk * 32 + fg * 8]);
#pragma unroll
            for (int ni = 0; ni < 4; ni++) {
                bf16x8 b = ldfrag(&Bs[(ni * 16 + fr) * 68 + kk * 32 + fg * 8]);
                acc[ni] = mfma16(a, b, acc[ni]);
            }
        }
        __syncthreads();
    }
    if (MODE == 2) {
#pragma unroll
        for (int ni = 0; ni < 4; ni++) {
            const int dd = ddt * 64 + ni * 16 + fr;
            const int r0 = wave * 16 + fg * 4;
            bf16x4 pk;
#pragma unroll
            for (int j = 0; j < 4; j++) pk[j] = f2bf(acc[ni][j]);
            *(bf16x4*)&wf[(size_t)bb * C_ * R_ + (size_t)dd * 64 + r0] = pk;
        }
    } else {
#pragma unroll
        for (int ni = 0; ni < 4; ni++)
#pragma unroll
            for (int j = 0; j < 4; j++) {
                const int r = wave * 16 + fg * 4 + j;
                const int dd = ddt * 64 + ni * 16 + fr;
                if (MODE == 0)
                    parts[(((size_t)bb * 8 + ch) * 64 + r) * 576 + dd] = acc[ni][j];
                else
                    btb[bb * R_ * R_ + r * 64 + dd] = f2bf(acc[ni][j]);
            }
    }
}

// ---------------------------------------------------------------------------
// k_bases_update
// ---------------------------------------------------------------------------
__global__ __launch_bounds__(256)
void k_bases_update(const float* __restrict__ parts, float* __restrict__ basesT,
                    short* __restrict__ basesTb) {
    const int dt = blockIdx.x, bb = blockIdx.y;
    __shared__ float ctcL[64 * 64];
    const int t = threadIdx.x;
    for (int idx = t; idx < 4096; idx += 256) {
        const int r = idx >> 6, s = idx & 63;
        float sum = 0.f;
#pragma unroll
        for (int ch = 0; ch < 8; ch++)
            sum += parts[(((size_t)bb * 8 + ch) * 64 + r) * 576 + 512 + s];
        ctcL[idx] = sum;
    }
    __syncthreads();
    float nv[16];
#pragma unroll
    for (int i = 0; i < 16; i++) {
        const int idx = t + i * 256;
        const int r = idx >> 6, d = dt * 64 + (idx & 63);
        float num = 0.f;
#pragma unroll
        for (int ch = 0; ch < 8; ch++)
            num += parts[(((size_t)bb * 8 + ch) * 64 + r) * 576 + d];
        float den = 0.f;
        const float* bcol = basesT + (size_t)bb * R_ * C_ + d;
        for (int s = 0; s < 64; s++)
            den += ctcL[r * 64 + s] * bcol[(size_t)s * C_];
        const float oldv = basesT[(size_t)bb * R_ * C_ + (size_t)r * C_ + d];
        nv[i] = oldv * num / (den + EPS);
    }
    __syncthreads();
#pragma unroll
    for (int i = 0; i < 16; i++) {
        const int idx = t + i * 256;
        const int r = idx >> 6, d = dt * 64 + (idx & 63);
        basesT[(size_t)bb * R_ * C_ + (size_t)r * C_ + d] = nv[i];
        basesTb[(size_t)bb * R_ * C_ + (size_t)r * C_ + d] = f2bf(nv[i]);
    }
}

// ---------------------------------------------------------------------------
// k_final: out[m][n] = relu(x + Wfused @ coef + b_out)  (K=64)
// acc D[row=n][col=m]: lane holds 4 consecutive n -> float4 I/O
// ---------------------------------------------------------------------------
__global__ __launch_bounds__(256)
void k_final(const short* __restrict__ wf, const short* __restrict__ coef,
             const float* __restrict__ X, const float* __restrict__ bias,
             float* __restrict__ out) {
    const int nb = blockIdx.x * 128, mb = blockIdx.y * 128, bb = blockIdx.z;
    __shared__ short As[128 * 68];
    __shared__ short Bs[128 * 68];
    const int t = threadIdx.x;
    const int lane = t & 63, wave = t >> 6;
    const int wm = wave >> 1, wn = wave & 1;
    const int fr = lane & 15, fg = lane >> 4;
    const short* wfb = wf + (size_t)bb * C_ * R_;
    const short* coefB = coef + (size_t)bb * R_ * N_;
    f32x4 zero4 = {0.f, 0.f, 0.f, 0.f};
    f32x4 acc[4][4];   // [ni][mi]
    for (int i = 0; i < 4; i++) for (int j = 0; j < 4; j++) acc[i][j] = zero4;

#pragma unroll
    for (int i = 0; i < 4; i++) {   // stage A = Wfused [128 rows m][64 r]
        const int kg = (t & 7) * 8, row = (t >> 3) + 32 * i;
        const short* src = wfb + (size_t)(mb + row) * 64 + kg;
        short* dst = &As[row * 68 + kg];
        *(bf16x4*)dst = *(const bf16x4*)src;
        *(bf16x4*)(dst + 4) = *(const bf16x4*)(src + 4);
    }
    {   // stage B transposed: coef[r][n] -> Bs[n*68+r]
        const int bn = 2 * (t & 15), bkp = t >> 4;
#pragma unroll
        for (int i = 0; i < 2; i++) {
            const int kp = bkp + 16 * i;
            const short* r0 = coefB + (size_t)(2 * kp) * N_ + nb + bn;
#pragma unroll
            for (int p = 0; p < 4; p++) {
                const unsigned ra = *(const unsigned*)(r0 + 32 * p);
                const unsigned rb = *(const unsigned*)(r0 + 32 * p + N_);
                *(unsigned*)&Bs[(bn + 32 * p) * 68 + 2 * kp] = (ra & 0xffffu) | (rb << 16);
                *(unsigned*)&Bs[(bn + 1 + 32 * p) * 68 + 2 * kp] = (ra >> 16) | (rb & 0xffff0000u);
            }
        }
    }
    __syncthreads();
#pragma unroll
    for (int kk = 0; kk < 2; kk++) {
        bf16x8 cf[4], af[4];
#pragma unroll
        for (int ni = 0; ni < 4; ni++) cf[ni] = ldfrag(&Bs[(wn * 64 + ni * 16 + fr) * 68 + kk * 32 + fg * 8]);
#pragma unroll
        for (int mi = 0; mi < 4; mi++) af[mi] = ldfrag(&As[(wm * 64 + mi * 16 + fr) * 68 + kk * 32 + fg * 8]);
#pragma unroll
        for (int ni = 0; ni < 4; ni++)
#pragma unroll
            for (int mi = 0; mi < 4; mi++)
                acc[ni][mi] = mfma16(cf[ni], af[mi], acc[ni][mi]);
    }
    const float* Xb = X + (size_t)bb * C_ * N_;
    float* Ob = out + (size_t)bb * C_ * N_;
#pragma unroll
    for (int mi = 0; mi < 4; mi++) {
        const int m = mb + wm * 64 + mi * 16 + fr;
        const float bvv = bias[m];
#pragma unroll
        for (int ni = 0; ni < 4; ni++) {
            const int n0 = nb + wn * 64 + ni * 16 + fg * 4;
            float4 xv = *(const float4*)&Xb[(size_t)m * N_ + n0];
            const float* xp = (const float*)&xv;
            float4 ov;
            float* op = (float*)&ov;
#pragma unroll
            for (int j = 0; j < 4; j++) {
                float v = xp[j] + acc[ni][mi][j] + bvv;
                op[j] = v > 0.f ? v : 0.f;
            }
            *(float4*)&Ob[(size_t)m * N_ + n0] = ov;
        }
    }
}

// ---------------------------------------------------------------------------
extern "C" void kernel_launch(void* const* d_in, const int* in_sizes, int n_in,
                              void* d_out, int out_size, void* d_ws, size_t ws_size,
                              hipStream_t stream) {
    const float* x     = (const float*)d_in[0];
    const float* w_in  = (const float*)d_in[1];
    const float* b_in  = (const float*)d_in[2];
    const float* w_out = (const float*)d_in[3];
    const float* b_out = (const float*)d_in[4];
    const float* bases = (const float*)d_in[5];
    float* out = (float*)d_out;

    short* ht      = (short*)d_ws;                     // [8][16384][512] bf16 (134.2 MB)
    short* coef    = ht + (size_t)67108864;            // 8388608 shorts (16.8 MB)
    float* basesT  = (float*)(coef + 8388608);         // 262144 floats (1 MB)
    short* basesTb = (short*)(basesT + 262144);        // 262144 shorts
    short* btb     = basesTb + 262144;                 // 32768 shorts
    short* wf      = btb + 32768;                      // 262144 shorts
    float* parts   = (float*)(wf + 262144);            // 2359296 floats (9.4 MB)
    short* wbf     = (short*)(parts + 2359296);        // 262144 shorts (0.5 MB)

    k_prep<<<1024, 256, 0, stream>>>(bases, basesT, basesTb, w_in, wbf);
    k_conv1<<<dim3(128, 4, 8), 256, 0, stream>>>(wbf, b_in, x, ht);
    k_coef<0><<<dim3(64, 8), 256, 0, stream>>>(basesTb, ht, btb, coef);
    for (int s = 0; s < 7; s++) {
        k_tn<1><<<dim3(1, 1, 8), 256, 0, stream>>>(coef, ht, basesTb, w_out, parts, btb, wf);
        k_coef<1><<<dim3(64, 8), 256, 0, stream>>>(basesTb, ht, btb, coef);
        k_tn<0><<<dim3(9, 8, 8), 256, 0, stream>>>(coef, ht, basesTb, w_out, parts, btb, wf);
        k_bases_update<<<dim3(8, 8), 256, 0, stream>>>(parts, basesT, basesTb);
    }
    k_tn<1><<<dim3(1, 1, 8), 256, 0, stream>>>(coef, ht, basesTb, w_out, parts, btb, wf);
    k_coef<1><<<dim3(64, 8), 256, 0, stream>>>(basesTb, ht, btb, coef);
    k_tn<2><<<dim3(8, 1, 8), 256, 0, stream>>>(coef, ht, basesTb, w_out, parts, btb, wf);
    k_final<<<dim3(128, 4, 8), 256, 0, stream>>>(wf, coef, x, b_out, out);
}

// Round 6
// 1570.128 us; speedup vs baseline: 1.0191x; 1.0191x over previous
//
#include <hip/hip_runtime.h>
#include <hip/hip_bf16.h>

#define B_ 8
#define C_ 512
#define N_ 16384
#define R_ 64
#define EPS 1e-6f

typedef float  f32x4  __attribute__((ext_vector_type(4)));
typedef short  bf16x4 __attribute__((ext_vector_type(4)));
typedef short  bf16x8 __attribute__((ext_vector_type(8)));

#define DI __device__ __forceinline__

DI short f2bf(float f) {
    union { float f; unsigned u; } a; a.f = f;
    unsigned r = a.u + 0x7fffu + ((a.u >> 16) & 1u);
    return (short)(r >> 16);
}
DI float bf2f(short s) {
    union { unsigned u; float f; } a;
    a.u = ((unsigned)(unsigned short)s) << 16;
    return a.f;
}
DI unsigned pk2(float lo, float hi) {
    union { __hip_bfloat162 h; unsigned u; } c;
    c.h = __float22bfloat162_rn(make_float2(lo, hi));
    return c.u;
}

union BV { bf16x8 v; bf16x4 h[2]; };
DI bf16x8 ldfrag(const short* p) {
    BV u;
    u.h[0] = *(const bf16x4*)p;
    u.h[1] = *(const bf16x4*)(p + 4);
    return u.v;
}
DI f32x4 mfma16(bf16x8 a, bf16x8 b, f32x4 c) {
    return __builtin_amdgcn_mfma_f32_16x16x32_bf16(a, b, c, 0, 0, 0);
}

// ---------------------------------------------------------------------------
// prep: bases [512][64] f32 -> basesT [8][64][512] f32 + bf16; w_in -> bf16
// ---------------------------------------------------------------------------
__global__ __launch_bounds__(256)
void k_prep(const float* __restrict__ bases, float* __restrict__ basesT,
            short* __restrict__ basesTb, const float* __restrict__ w_in,
            short* __restrict__ wbf) {
    int idx = blockIdx.x * 256 + threadIdx.x;        // 262144
    const int d = idx & 511;
    const int r = (idx >> 9) & 63;
    const float v = bases[d * 64 + r];
    basesT[idx]  = v;
    basesTb[idx] = f2bf(v);
    wbf[idx] = f2bf(w_in[idx]);
}

// ---------------------------------------------------------------------------
// conv1: Ht[n][c] = relu(Win @ X + b_in)^T  — 2-phase pipelined staging
// ---------------------------------------------------------------------------
__global__ __launch_bounds__(256)
void k_conv1(const short* __restrict__ Wbf, const float* __restrict__ bias,
             const float* __restrict__ X, short* __restrict__ Ht) {
    const int nb = blockIdx.x * 128, mb = blockIdx.y * 128, bb = blockIdx.z;
    const float* Xb = X + (size_t)bb * C_ * N_;
    short* HtB = Ht + (size_t)bb * N_ * C_;
    __shared__ short As[2][128 * 36];
    __shared__ short Bs[2][128 * 36];
    const int t = threadIdx.x;
    const int lane = t & 63, wave = t >> 6;
    const int wm = wave >> 1, wn = wave & 1;
    const int fr = lane & 15, fg = lane >> 4;
    f32x4 zero4 = {0.f, 0.f, 0.f, 0.f};
    f32x4 acc[4][4];
    for (int i = 0; i < 4; i++) for (int j = 0; j < 4; j++) acc[i][j] = zero4;

    const int an_row = t >> 2, an_kc = (t & 3) * 8;
    const int bkp = t >> 4;

    auto LD = [&](int kb, bf16x8 (&a)[2], float4 (&f)[4]) {
#pragma unroll
        for (int i = 0; i < 2; i++)
            a[i] = *(const bf16x8*)(Wbf + (size_t)(mb + an_row + 64 * i) * C_ + kb + an_kc);
#pragma unroll
        for (int i = 0; i < 2; i++) {
            const int n0 = 4 * ((t & 15) + 16 * i);
            const float* r0 = Xb + (size_t)(kb + 2 * bkp) * N_ + nb + n0;
            f[2 * i]     = *(const float4*)r0;
            f[2 * i + 1] = *(const float4*)(r0 + N_);
        }
    };
    auto ST = [&](short* Asb, short* Bsb, const bf16x8 (&a)[2], const float4 (&f)[4]) {
#pragma unroll
        for (int i = 0; i < 2; i++) {
            BV u; u.v = a[i];
            short* dst = &Asb[(an_row + 64 * i) * 36 + an_kc];
            *(bf16x4*)dst = u.h[0]; *(bf16x4*)(dst + 4) = u.h[1];
        }
#pragma unroll
        for (int i = 0; i < 2; i++) {
            const int n0 = 4 * ((t & 15) + 16 * i);
            const float* pa = (const float*)&f[2 * i];
            const float* pb = (const float*)&f[2 * i + 1];
#pragma unroll
            for (int j = 0; j < 4; j++)
                *(unsigned*)&Bsb[(n0 + j) * 36 + 2 * bkp] = pk2(pa[j], pb[j]);
        }
    };

    bf16x8 a0[2], a1[2]; float4 f0[4], f1[4];
    LD(0, a0, f0);
    ST(As[0], Bs[0], a0, f0);
    LD(32, a1, f1);
    __syncthreads();

#pragma unroll
    for (int i = 0; i < 16; i++) {
        const int cur = i & 1;
        if (cur == 0) {
            if (i < 15) ST(As[1], Bs[1], a1, f1);
            if (i < 14) LD((i + 2) * 32, a0, f0);
        } else {
            if (i < 15) ST(As[0], Bs[0], a0, f0);
            if (i < 14) LD((i + 2) * 32, a1, f1);
        }
        bf16x8 af[4], bv[4];
#pragma unroll
        for (int mi = 0; mi < 4; mi++) af[mi] = ldfrag(&As[cur][(wm * 64 + mi * 16 + fr) * 36 + fg * 8]);
#pragma unroll
        for (int ni = 0; ni < 4; ni++) bv[ni] = ldfrag(&Bs[cur][(wn * 64 + ni * 16 + fr) * 36 + fg * 8]);
#pragma unroll
        for (int mi = 0; mi < 4; mi++)
#pragma unroll
            for (int ni = 0; ni < 4; ni++)
                acc[mi][ni] = mfma16(af[mi], bv[ni], acc[mi][ni]);
        __syncthreads();
    }
    // epilogue: packed b64 stores to Ht[n][c]
#pragma unroll
    for (int mi = 0; mi < 4; mi++) {
        const int c0 = mb + wm * 64 + mi * 16 + fg * 4;
        const float4 b4 = *(const float4*)&bias[c0];
        const float* bp = (const float*)&b4;
#pragma unroll
        for (int ni = 0; ni < 4; ni++) {
            const int n = nb + wn * 64 + ni * 16 + fr;
            bf16x4 pk;
#pragma unroll
            for (int j = 0; j < 4; j++) {
                float v = acc[mi][ni][j] + bp[j];
                pk[j] = f2bf(v > 0.f ? v : 0.f);
            }
            *(bf16x4*)&HtB[(size_t)n * C_ + c0] = pk;
        }
    }
}

// ---------------------------------------------------------------------------
// k_coef: num[n][r] = Ht @ basesT^T (K=512, pipelined); UPDATE: den via btb,
// coef *= num/(den+eps); else softmax_r.
// ---------------------------------------------------------------------------
template<int UPDATE>
__global__ __launch_bounds__(256)
void k_coef(const short* __restrict__ basesTb, const short* __restrict__ Ht,
            const short* __restrict__ btb, short* __restrict__ coef) {
    const int nb = blockIdx.x * 256, bb = blockIdx.y;
    const short* HtB = Ht + (size_t)bb * N_ * C_;
    const short* bT = basesTb + (size_t)bb * R_ * C_;
    short* coefB = coef + (size_t)bb * R_ * N_;
    __shared__ short As[2][64 * 36];
    __shared__ short Bs[2][256 * 44];
    __shared__ short Ds[64 * 68];
    const int t = threadIdx.x;
    const int lane = t & 63, wave = t >> 6;
    const int fr = lane & 15, fg = lane >> 4;
    f32x4 zero4 = {0.f, 0.f, 0.f, 0.f};
    f32x4 accN[4][4];   // [nt][rt]
    for (int i = 0; i < 4; i++) for (int j = 0; j < 4; j++) accN[i][j] = zero4;

    const int arow = t >> 2, akc = (t & 3) * 8;

    auto LD1 = [&](int kb, bf16x8& a, bf16x8 (&b)[4]) {
        a = *(const bf16x8*)(bT + arow * C_ + kb + akc);
        const short* src = HtB + (size_t)(nb + t) * C_ + kb;
#pragma unroll
        for (int s = 0; s < 4; s++) b[s] = *(const bf16x8*)(src + 8 * s);
    };
    auto ST1 = [&](short* Asb, short* Bsb, bf16x8 a, const bf16x8 (&b)[4]) {
        BV u; u.v = a;
        short* ad = &Asb[arow * 36 + akc];
        *(bf16x4*)ad = u.h[0]; *(bf16x4*)(ad + 4) = u.h[1];
        short* dst = &Bsb[t * 44];
#pragma unroll
        for (int s = 0; s < 4; s++) {
            BV w; w.v = b[s];
            *(bf16x4*)(dst + 8 * s) = w.h[0];
            *(bf16x4*)(dst + 8 * s + 4) = w.h[1];
        }
    };

    bf16x8 a0, a1, b0[4], b1[4];
    LD1(0, a0, b0);
    ST1(As[0], Bs[0], a0, b0);
    LD1(32, a1, b1);
    __syncthreads();

#pragma unroll
    for (int i = 0; i < 16; i++) {
        const int cur = i & 1;
        if (cur == 0) {
            if (i < 15) ST1(As[1], Bs[1], a1, b1);
            if (i < 14) LD1((i + 2) * 32, a0, b0);
        } else {
            if (i < 15) ST1(As[0], Bs[0], a0, b0);
            if (i < 14) LD1((i + 2) * 32, a1, b1);
        }
        bf16x8 hf[4], bfr[4];
#pragma unroll
        for (int nt = 0; nt < 4; nt++) hf[nt] = ldfrag(&Bs[cur][(wave * 64 + nt * 16 + fr) * 44 + fg * 8]);
#pragma unroll
        for (int rt = 0; rt < 4; rt++) bfr[rt] = ldfrag(&As[cur][(rt * 16 + fr) * 36 + fg * 8]);
#pragma unroll
        for (int nt = 0; nt < 4; nt++)
#pragma unroll
            for (int rt = 0; rt < 4; rt++)
                accN[nt][rt] = mfma16(hf[nt], bfr[rt], accN[nt][rt]);
        __syncthreads();
    }

    if (UPDATE) {
        f32x4 accD[4][4];
        for (int i = 0; i < 4; i++) for (int j = 0; j < 4; j++) accD[i][j] = zero4;
        {   // stage btb [64][64] -> Ds (stride 68)
            const short* bt = btb + bb * R_ * R_;
#pragma unroll
            for (int i = 0; i < 2; i++) {
                const int row = t & 63, kc8 = ((t >> 6) + 4 * i) * 8;
                const short* src = bt + row * 64 + kc8;
                short* dst = &Ds[row * 68 + kc8];
                *(bf16x4*)dst = *(const bf16x4*)src;
                *(bf16x4*)(dst + 4) = *(const bf16x4*)(src + 4);
            }
        }
        // phase 2: den[n][r], two K=32 substeps via Bs[0]
        for (int ks = 0; ks < 2; ks++) {
            const int sp = t >> 4;
            const int s0 = ks * 32 + 2 * sp;
#pragma unroll
            for (int p = 0; p < 8; p++) {
                const int n0 = 2 * ((t & 15) + 16 * p);
                const unsigned ra = *(const unsigned*)(coefB + (size_t)s0 * N_ + nb + n0);
                const unsigned rb = *(const unsigned*)(coefB + (size_t)(s0 + 1) * N_ + nb + n0);
                *(unsigned*)&Bs[0][n0 * 44 + 2 * sp] = (ra & 0xffffu) | (rb << 16);
                *(unsigned*)&Bs[0][(n0 + 1) * 44 + 2 * sp] = (ra >> 16) | (rb & 0xffff0000u);
            }
            __syncthreads();
            bf16x8 cf[4], df[4];
#pragma unroll
            for (int nt = 0; nt < 4; nt++) cf[nt] = ldfrag(&Bs[0][(wave * 64 + nt * 16 + fr) * 44 + fg * 8]);
#pragma unroll
            for (int rt = 0; rt < 4; rt++) df[rt] = ldfrag(&Ds[(rt * 16 + fr) * 68 + ks * 32 + fg * 8]);
#pragma unroll
            for (int nt = 0; nt < 4; nt++)
#pragma unroll
                for (int rt = 0; rt < 4; rt++)
                    accD[nt][rt] = mfma16(cf[nt], df[rt], accD[nt][rt]);
            __syncthreads();
        }
        // phase 3: multiplicative update, b64 packed RMW
#pragma unroll
        for (int nt = 0; nt < 4; nt++)
#pragma unroll
            for (int rt = 0; rt < 4; rt++) {
                const int r = rt * 16 + fr;
                const int n0 = nb + wave * 64 + nt * 16 + fg * 4;
                short* p = coefB + (size_t)r * N_ + n0;
                bf16x4 old = *(const bf16x4*)p;
                bf16x4 nw;
#pragma unroll
                for (int j = 0; j < 4; j++)
                    nw[j] = f2bf(bf2f(old[j]) * accN[nt][rt][j] / (accD[nt][rt][j] + EPS));
                *(bf16x4*)p = nw;
            }
    } else {
        // softmax over r per column n
#pragma unroll
        for (int nt = 0; nt < 4; nt++) {
            float mx[4], sm[4];
#pragma unroll
            for (int j = 0; j < 4; j++) {
                float m = accN[nt][0][j];
#pragma unroll
                for (int rt = 1; rt < 4; rt++) m = fmaxf(m, accN[nt][rt][j]);
                m = fmaxf(m, __shfl_xor(m, 1, 64));
                m = fmaxf(m, __shfl_xor(m, 2, 64));
                m = fmaxf(m, __shfl_xor(m, 4, 64));
                m = fmaxf(m, __shfl_xor(m, 8, 64));
                mx[j] = m; sm[j] = 0.f;
            }
#pragma unroll
            for (int rt = 0; rt < 4; rt++)
#pragma unroll
                for (int j = 0; j < 4; j++) {
                    float e = __expf(accN[nt][rt][j] - mx[j]);
                    accN[nt][rt][j] = e;
                    sm[j] += e;
                }
#pragma unroll
            for (int j = 0; j < 4; j++) {
                float s = sm[j];
                s += __shfl_xor(s, 1, 64);
                s += __shfl_xor(s, 2, 64);
                s += __shfl_xor(s, 4, 64);
                s += __shfl_xor(s, 8, 64);
                sm[j] = 1.f / s;
            }
#pragma unroll
            for (int rt = 0; rt < 4; rt++) {
                const int r = rt * 16 + fr;
                const int n0 = nb + wave * 64 + nt * 16 + fg * 4;
                bf16x4 pk;
#pragma unroll
                for (int j = 0; j < 4; j++) pk[j] = f2bf(accN[nt][rt][j] * sm[j]);
                *(bf16x4*)&coefB[(size_t)r * N_ + n0] = pk;
            }
        }
    }
}

// ---------------------------------------------------------------------------
// k_tn: C[r][dd] = sum_k A[r,k]*B[dd,k] — pipelined staging
// MODE 0: A=coef, B=[H(Ht^T) ; coef] (576 rows), split-K partials
// MODE 1: A=B=basesT -> btb (B-frags read from As)
// MODE 2: A=basesT, B=Wout(f32) -> Wfused [o][r]
// ---------------------------------------------------------------------------
template<int MODE>
__global__ __launch_bounds__(256)
void k_tn(const short* __restrict__ coef, const short* __restrict__ Ht,
          const short* __restrict__ basesTb, const float* __restrict__ Wout,
          float* __restrict__ parts, short* __restrict__ btb, short* __restrict__ wf) {
    const int ddt = blockIdx.x, ch = blockIdx.y, bb = blockIdx.z;
    const int kSteps = (MODE == 0) ? 32 : 8;
    const int k0g = ch * ((MODE == 0) ? 2048 : 512);
    const short* Ap; int lda;
    if (MODE == 0) { Ap = coef + (size_t)bb * R_ * N_; lda = N_; }
    else           { Ap = basesTb + (size_t)bb * R_ * C_; lda = C_; }
    const short* HtB = Ht + (size_t)bb * N_ * C_;
    const short* coefB = coef + (size_t)bb * R_ * N_;
    __shared__ short As[2][64 * 68];
    __shared__ short Bs[2][64 * 68];
    const int t = threadIdx.x;
    const int lane = t & 63, wave = t >> 6;
    const int fr = lane & 15, fg = lane >> 4;
    f32x4 zero4 = {0.f, 0.f, 0.f, 0.f};
    f32x4 acc[4];
    for (int i = 0; i < 4; i++) acc[i] = zero4;

    const int kg = (t & 7) * 8, rr = t >> 3;

    struct TReg { bf16x8 a[2]; unsigned bu[8]; float4 bf[4]; };

    auto LDT = [&](int kb, TReg& R) {
#pragma unroll
        for (int i = 0; i < 2; i++)
            R.a[i] = *(const bf16x8*)(Ap + (size_t)(rr + 32 * i) * lda + k0g + kb + kg);
        if (MODE == 0) {
            if (ddt < 8) {
                const int dd0 = 2 * (t & 31);
#pragma unroll
                for (int i = 0; i < 4; i++) {
                    const int n0 = 2 * ((t >> 5) + 8 * i);
                    R.bu[2 * i]     = *(const unsigned*)(HtB + (size_t)(k0g + kb + n0) * C_ + ddt * 64 + dd0);
                    R.bu[2 * i + 1] = *(const unsigned*)(HtB + (size_t)(k0g + kb + n0 + 1) * C_ + ddt * 64 + dd0);
                }
            } else {
#pragma unroll
                for (int i = 0; i < 2; i++) {
                    const unsigned* src = (const unsigned*)(coefB + (size_t)(rr + 32 * i) * N_ + k0g + kb + kg);
#pragma unroll
                    for (int q = 0; q < 4; q++) R.bu[4 * i + q] = src[q];
                }
            }
        } else if (MODE == 2) {
#pragma unroll
            for (int i = 0; i < 2; i++) {
                const float* src = Wout + (size_t)(ddt * 64 + rr + 32 * i) * C_ + kb + kg;
                R.bf[2 * i]     = *(const float4*)src;
                R.bf[2 * i + 1] = *(const float4*)(src + 4);
            }
        }
    };
    auto STT = [&](short* Asb, short* Bsb, const TReg& R) {
#pragma unroll
        for (int i = 0; i < 2; i++) {
            BV u; u.v = R.a[i];
            short* dst = &Asb[(rr + 32 * i) * 68 + kg];
            *(bf16x4*)dst = u.h[0]; *(bf16x4*)(dst + 4) = u.h[1];
        }
        if (MODE == 0) {
            if (ddt < 8) {
                const int dd0 = 2 * (t & 31);
#pragma unroll
                for (int i = 0; i < 4; i++) {
                    const int n0 = 2 * ((t >> 5) + 8 * i);
                    const unsigned ra = R.bu[2 * i], rb = R.bu[2 * i + 1];
                    *(unsigned*)&Bsb[dd0 * 68 + n0] = (ra & 0xffffu) | (rb << 16);
                    *(unsigned*)&Bsb[(dd0 + 1) * 68 + n0] = (ra >> 16) | (rb & 0xffff0000u);
                }
            } else {
#pragma unroll
                for (int i = 0; i < 2; i++) {
                    unsigned* dst = (unsigned*)&Bsb[(rr + 32 * i) * 68 + kg];
#pragma unroll
                    for (int q = 0; q < 4; q++) dst[q] = R.bu[4 * i + q];
                }
            }
        } else if (MODE == 2) {
#pragma unroll
            for (int i = 0; i < 2; i++) {
                short* dst = &Bsb[(rr + 32 * i) * 68 + kg];
                const float* p0 = (const float*)&R.bf[2 * i];
                const float* p1 = (const float*)&R.bf[2 * i + 1];
                *(unsigned*)dst       = pk2(p0[0], p0[1]);
                *(unsigned*)(dst + 2) = pk2(p0[2], p0[3]);
                *(unsigned*)(dst + 4) = pk2(p1[0], p1[1]);
                *(unsigned*)(dst + 6) = pk2(p1[2], p1[3]);
            }
        }
    };

    TReg R0, R1;
    LDT(0, R0);
    STT(As[0], Bs[0], R0);
    LDT(64, R1);
    __syncthreads();

#pragma unroll
    for (int i = 0; i < kSteps; i++) {
        const int cur = i & 1;
        if (cur == 0) {
            if (i < kSteps - 1) STT(As[1], Bs[1], R1);
            if (i < kSteps - 2) LDT((i + 2) * 64, R0);
        } else {
            if (i < kSteps - 1) STT(As[0], Bs[0], R0);
            if (i < kSteps - 2) LDT((i + 2) * 64, R1);
        }
#pragma unroll
        for (int kk = 0; kk < 2; kk++) {
            bf16x8 a = ldfrag(&As[cur][(wave * 16 + fr) * 68 + kk * 32 + fg * 8]);
#pragma unroll
            for (int ni = 0; ni < 4; ni++) {
                const short* bp = (MODE == 1) ? &As[cur][(ni * 16 + fr) * 68 + kk * 32 + fg * 8]
                                              : &Bs[cur][(ni * 16 + fr) * 68 + kk * 32 + fg * 8];
                bf16x8 b = ldfrag(bp);
                acc[ni] = mfma16(a, b, acc[ni]);
            }
        }
        __syncthreads();
    }
    if (MODE == 2) {
#pragma unroll
        for (int ni = 0; ni < 4; ni++) {
            const int dd = ddt * 64 + ni * 16 + fr;
            const int r0 = wave * 16 + fg * 4;
            bf16x4 pk;
#pragma unroll
            for (int j = 0; j < 4; j++) pk[j] = f2bf(acc[ni][j]);
            *(bf16x4*)&wf[(size_t)bb * C_ * R_ + (size_t)dd * 64 + r0] = pk;
        }
    } else {
#pragma unroll
        for (int ni = 0; ni < 4; ni++)
#pragma unroll
            for (int j = 0; j < 4; j++) {
                const int r = wave * 16 + fg * 4 + j;
                const int dd = ddt * 64 + ni * 16 + fr;
                if (MODE == 0)
                    parts[(((size_t)bb * 8 + ch) * 64 + r) * 576 + dd] = acc[ni][j];
                else
                    btb[bb * R_ * R_ + r * 64 + dd] = f2bf(acc[ni][j]);
            }
    }
}

// ---------------------------------------------------------------------------
// k_bases_update
// ---------------------------------------------------------------------------
__global__ __launch_bounds__(256)
void k_bases_update(const float* __restrict__ parts, float* __restrict__ basesT,
                    short* __restrict__ basesTb) {
    const int dt = blockIdx.x, bb = blockIdx.y;
    __shared__ float ctcL[64 * 64];
    const int t = threadIdx.x;
    for (int idx = t; idx < 4096; idx += 256) {
        const int r = idx >> 6, s = idx & 63;
        float sum = 0.f;
#pragma unroll
        for (int ch = 0; ch < 8; ch++)
            sum += parts[(((size_t)bb * 8 + ch) * 64 + r) * 576 + 512 + s];
        ctcL[idx] = sum;
    }
    __syncthreads();
    float nv[16];
#pragma unroll
    for (int i = 0; i < 16; i++) {
        const int idx = t + i * 256;
        const int r = idx >> 6, d = dt * 64 + (idx & 63);
        float num = 0.f;
#pragma unroll
        for (int ch = 0; ch < 8; ch++)
            num += parts[(((size_t)bb * 8 + ch) * 64 + r) * 576 + d];
        float den = 0.f;
        const float* bcol = basesT + (size_t)bb * R_ * C_ + d;
        for (int s = 0; s < 64; s++)
            den += ctcL[r * 64 + s] * bcol[(size_t)s * C_];
        const float oldv = basesT[(size_t)bb * R_ * C_ + (size_t)r * C_ + d];
        nv[i] = oldv * num / (den + EPS);
    }
    __syncthreads();
#pragma unroll
    for (int i = 0; i < 16; i++) {
        const int idx = t + i * 256;
        const int r = idx >> 6, d = dt * 64 + (idx & 63);
        basesT[(size_t)bb * R_ * C_ + (size_t)r * C_ + d] = nv[i];
        basesTb[(size_t)bb * R_ * C_ + (size_t)r * C_ + d] = f2bf(nv[i]);
    }
}

// ---------------------------------------------------------------------------
// k_final: out[m][n] = relu(x + Wfused @ coef + b_out)  (K=64)
// ---------------------------------------------------------------------------
__global__ __launch_bounds__(256)
void k_final(const short* __restrict__ wf, const short* __restrict__ coef,
             const float* __restrict__ X, const float* __restrict__ bias,
             float* __restrict__ out) {
    const int nb = blockIdx.x * 128, mb = blockIdx.y * 128, bb = blockIdx.z;
    __shared__ short As[128 * 68];
    __shared__ short Bs[128 * 68];
    const int t = threadIdx.x;
    const int lane = t & 63, wave = t >> 6;
    const int wm = wave >> 1, wn = wave & 1;
    const int fr = lane & 15, fg = lane >> 4;
    const short* wfb = wf + (size_t)bb * C_ * R_;
    const short* coefB = coef + (size_t)bb * R_ * N_;
    f32x4 zero4 = {0.f, 0.f, 0.f, 0.f};
    f32x4 acc[4][4];   // [ni][mi]
    for (int i = 0; i < 4; i++) for (int j = 0; j < 4; j++) acc[i][j] = zero4;

#pragma unroll
    for (int i = 0; i < 4; i++) {   // stage A = Wfused [128 m][64 r]
        const int kg = (t & 7) * 8, row = (t >> 3) + 32 * i;
        const short* src = wfb + (size_t)(mb + row) * 64 + kg;
        short* dst = &As[row * 68 + kg];
        *(bf16x4*)dst = *(const bf16x4*)src;
        *(bf16x4*)(dst + 4) = *(const bf16x4*)(src + 4);
    }
    {   // stage B transposed: coef[r][n] -> Bs[n*68+r]
        const int bn = 2 * (t & 15), bkp = t >> 4;
#pragma unroll
        for (int i = 0; i < 2; i++) {
            const int kp = bkp + 16 * i;
            const short* r0 = coefB + (size_t)(2 * kp) * N_ + nb + bn;
#pragma unroll
            for (int p = 0; p < 4; p++) {
                const unsigned ra = *(const unsigned*)(r0 + 32 * p);
                const unsigned rb = *(const unsigned*)(r0 + 32 * p + N_);
                *(unsigned*)&Bs[(bn + 32 * p) * 68 + 2 * kp] = (ra & 0xffffu) | (rb << 16);
                *(unsigned*)&Bs[(bn + 1 + 32 * p) * 68 + 2 * kp] = (ra >> 16) | (rb & 0xffff0000u);
            }
        }
    }
    __syncthreads();
#pragma unroll
    for (int kk = 0; kk < 2; kk++) {
        bf16x8 cf[4], af[4];
#pragma unroll
        for (int ni = 0; ni < 4; ni++) cf[ni] = ldfrag(&Bs[(wn * 64 + ni * 16 + fr) * 68 + kk * 32 + fg * 8]);
#pragma unroll
        for (int mi = 0; mi < 4; mi++) af[mi] = ldfrag(&As[(wm * 64 + mi * 16 + fr) * 68 + kk * 32 + fg * 8]);
#pragma unroll
        for (int ni = 0; ni < 4; ni++)
#pragma unroll
            for (int mi = 0; mi < 4; mi++)
                acc[ni][mi] = mfma16(cf[ni], af[mi], acc[ni][mi]);
    }
    const float* Xb = X + (size_t)bb * C_ * N_;
    float* Ob = out + (size_t)bb * C_ * N_;
#pragma unroll
    for (int mi = 0; mi < 4; mi++) {
        const int m = mb + wm * 64 + mi * 16 + fr;
        const float bvv = bias[m];
#pragma unroll
        for (int ni = 0; ni < 4; ni++) {
            const int n0 = nb + wn * 64 + ni * 16 + fg * 4;
            float4 xv = *(const float4*)&Xb[(size_t)m * N_ + n0];
            const float* xp = (const float*)&xv;
            float4 ov;
            float* op = (float*)&ov;
#pragma unroll
            for (int j = 0; j < 4; j++) {
                float v = xp[j] + acc[ni][mi][j] + bvv;
                op[j] = v > 0.f ? v : 0.f;
            }
            *(float4*)&Ob[(size_t)m * N_ + n0] = ov;
        }
    }
}

// ---------------------------------------------------------------------------
extern "C" void kernel_launch(void* const* d_in, const int* in_sizes, int n_in,
                              void* d_out, int out_size, void* d_ws, size_t ws_size,
                              hipStream_t stream) {
    const float* x     = (const float*)d_in[0];
    const float* w_in  = (const float*)d_in[1];
    const float* b_in  = (const float*)d_in[2];
    const float* w_out = (const float*)d_in[3];
    const float* b_out = (const float*)d_in[4];
    const float* bases = (const float*)d_in[5];
    float* out = (float*)d_out;

    short* ht      = (short*)d_ws;                     // [8][16384][512] bf16 (134.2 MB)
    short* coef    = ht + (size_t)67108864;            // 8388608 shorts (16.8 MB)
    float* basesT  = (float*)(coef + 8388608);         // 262144 floats (1 MB)
    short* basesTb = (short*)(basesT + 262144);        // 262144 shorts
    short* btb     = basesTb + 262144;                 // 32768 shorts
    short* wf      = btb + 32768;                      // 262144 shorts
    float* parts   = (float*)(wf + 262144);            // 2359296 floats (9.4 MB)
    short* wbf     = (short*)(parts + 2359296);        // 262144 shorts (0.5 MB)

    k_prep<<<1024, 256, 0, stream>>>(bases, basesT, basesTb, w_in, wbf);
    k_conv1<<<dim3(128, 4, 8), 256, 0, stream>>>(wbf, b_in, x, ht);
    k_coef<0><<<dim3(64, 8), 256, 0, stream>>>(basesTb, ht, btb, coef);
    for (int s = 0; s < 7; s++) {
        k_tn<1><<<dim3(1, 1, 8), 256, 0, stream>>>(coef, ht, basesTb, w_out, parts, btb, wf);
        k_coef<1><<<dim3(64, 8), 256, 0, stream>>>(basesTb, ht, btb, coef);
        k_tn<0><<<dim3(9, 8, 8), 256, 0, stream>>>(coef, ht, basesTb, w_out, parts, btb, wf);
        k_bases_update<<<dim3(8, 8), 256, 0, stream>>>(parts, basesT, basesTb);
    }
    k_tn<1><<<dim3(1, 1, 8), 256, 0, stream>>>(coef, ht, basesTb, w_out, parts, btb, wf);
    k_coef<1><<<dim3(64, 8), 256, 0, stream>>>(basesTb, ht, btb, coef);
    k_tn<2><<<dim3(8, 1, 8), 256, 0, stream>>>(coef, ht, basesTb, w_out, parts, btb, wf);
    k_final<<<dim3(128, 4, 8), 256, 0, stream>>>(wf, coef, x, b_out, out);
}